// Round 5
// baseline (192.226 us; speedup 1.0000x reference)
//
#include <hip/hip_runtime.h>

// ---------------------------------------------------------------------------
// NearestSim: out[t] = -cos(q_t, items[argmax_j q_t . items_j])
// T=16384, M=4096, C=512, fp32 in/out.
// R16 = 32x32x16 MFMA restructure. R15's (256,4) cap spilled ~24 regs/thread
// (WRITE_SIZE 9.6->105 MB) because 16x16x32 needs 64 frag regs + 64 acc.
// 32x32x16 halves operand regs for the same 64x64 wave tile (2x2 frags of
// 4 VGPR): 64 acc + 40 frag (depth-2 B prefetch) + addr ~= 120 < 128
// -> 4 blocks/CU with NO spill, and ~17% fewer MFMA-pipe cycles
// (128 x 8.07cyc vs 256 x 4.85cyc; ubench 2382 vs 2075 TF).
// Layouts: A row=lane&31, k=8*(lane>>5)+i ; C/D row=(r&3)+8*(r>>2)+4*(lane>>5),
// col=lane&31 (measured m74/m101, dtype-independent).
// ---------------------------------------------------------------------------

#define TQ 16384
#define MI 4096
#define CD 512
#define NIS 16          // item splits; block covers 256 items
#define BM 64           // block query rows

typedef _Float16 half8   __attribute__((ext_vector_type(8)));
typedef _Float16 half4_t __attribute__((ext_vector_type(4)));
typedef float    float16t __attribute__((ext_vector_type(16)));

// workspace layout (bytes)
#define QH_OFF   (0u)
#define QH_BYTES ((unsigned)TQ * CD * 2u)          // 16 MB fp16 queries (row-major)
#define IH_OFF   (QH_OFF + QH_BYTES)
#define IH_BYTES ((unsigned)MI * CD * 2u)          // 4 MB fp16 items (fragment order)
#define PART_OFF (IH_OFF + IH_BYTES)
#define PART_BYTES ((unsigned)TQ * 64u * 8u)       // 8 MB: 64 float2 / query
// total 28 MB

__device__ __forceinline__ void lds_load16(const void* g, void* l) {
  __builtin_amdgcn_global_load_lds(
      (const __attribute__((address_space(1))) void*)g,
      (__attribute__((address_space(3))) void*)l, 16, 0, 0);
}

template <int SWZ>
__device__ __forceinline__ float swz_f(float x) {
  return __int_as_float(__builtin_amdgcn_ds_swizzle(__float_as_int(x), SWZ));
}

// ---------------- kernel 1: fp32 -> fp16 conversion -------------------------
// Q: row-major half4 copy.
// Items: 32-wide fragment order for mfma_32x32x16:
//   chunk ic = g*4096 + k16*128 + ni*64 + lane   (byte addr = ic*16)
//   lane holds item row g*64 + ni*32 + (lane&31),
//   cols k16*16 + (lane>>5)*8 .. +8.
__global__ __launch_bounds__(256) void convert_kernel(
    const float* __restrict__ q, const float* __restrict__ it,
    char* __restrict__ ws) {
  const int idx = blockIdx.x * 256 + threadIdx.x;
  const int QV = TQ * CD / 4;   // Q: one half4 per thread
  const int IC = MI * CD / 8;   // items: one 16B chunk per thread
  if (idx < QV) {
    float4 v = ((const float4*)q)[idx];
    half4_t h = {(_Float16)v.x, (_Float16)v.y, (_Float16)v.z, (_Float16)v.w};
    ((half4_t*)(ws + QH_OFF))[idx] = h;
  }
  const int ic = idx - QV;
  if (ic >= 0 && ic < IC) {
    const int lane = ic & 63;
    const int ni   = (ic >> 6) & 1;
    const int k16  = (ic >> 7) & 31;
    const int g    = ic >> 12;                    // 0..63
    const int row  = g * 64 + ni * 32 + (lane & 31);
    const int col  = k16 * 16 + (lane >> 5) * 8;
    const float4* s = (const float4*)(it + (size_t)row * CD + col);
    float4 v0 = s[0], v1 = s[1];
    half8 h = {(_Float16)v0.x, (_Float16)v0.y, (_Float16)v0.z, (_Float16)v0.w,
               (_Float16)v1.x, (_Float16)v1.y, (_Float16)v1.z, (_Float16)v1.w};
    *(half8*)(ws + IH_OFF + (size_t)ic * 16) = h;
  }
}

// ---------------- kernel 2: barrier-free fused GEMM + packed top-2 ----------
// grid (TQ/BM, NIS), block 256 = 4 waves; wave tile 64q x 64i = 2x2 MFMAs of
// 32x32x16 (64 acc regs). A half-K image in 32 KB LDS (two phases), B direct
// global: one rolling voffset (+2048/kstep), ni via imm 0/1024, depth-2
// prefetch from imm 0/1024 after a +4096 prologue roll (all imms <= 3072).
// LDS image (per phase): phys(row,c) = row*512 + ((c ^ (row&15))*16), c=0..31
// -> 16-chunk spread per 16-lane group on b128 reads (conflict-free).
__global__ __launch_bounds__(256, 4) void score_kernel(char* __restrict__ ws) {
  __shared__ __align__(16) char sA[BM * 512];  // 32 KB: 64 rows x 256 fp16

  const int tid  = threadIdx.x;
  const int lane = tid & 63;
  const int wave = tid >> 6;
  const int l31  = lane & 31;
  const int half = lane >> 5;
  const int swz  = lane & 15;
  const int qtile = blockIdx.x;
  const int isplit = blockIdx.y;

  // staging map: instr j, thread t -> phys = j*4096 + t*16
  //   row = j*8 + (t>>5), phys chunk = t&31,
  //   logical c = (t&31) ^ (t>>5) ^ ((j&1)<<3)   (involution of row&15 swizzle)
  const char* Qbase = ws + QH_OFF + (size_t)qtile * BM * 1024;
  const int u = tid >> 5;                          // 0..7
  const int p = tid & 31;
  const char* gQ0 = Qbase + u * 1024 + (p ^ u) * 16;           // even j
  const char* gQ1 = Qbase + 8192 + u * 1024 + ((p ^ u) ^ 8) * 16;  // odd j
  const int ldst = tid * 16;                       // + j*4096

  // B stream: group g = isplit*4 + wave; rolling voffset, ni via imm offset.
  const char* Ibase = ws + IH_OFF;
  int bOff = ((isplit * 4 + wave) << 16) + lane * 16;

  // A fragment: phys = mi*16384 + l31*512 + ((((k16<<1)|half) ^ swz) << 4)
  const int aRowB = l31 * 512;

  float16t acc[2][2];
#pragma unroll
  for (int mi = 0; mi < 2; ++mi)
#pragma unroll
    for (int ni = 0; ni < 2; ++ni) acc[mi][ni] = (float16t)(0.0f);

  half8 aC[2], aN[2], bC[2], bN[2], bN2[2];
  // prologue: load b(k0), b(k1) while phase-0 staging is in flight
#pragma unroll
  for (int ni = 0; ni < 2; ++ni)
    bC[ni] = *(const half8*)(Ibase + bOff + ni * 1024);
#pragma unroll
  for (int ni = 0; ni < 2; ++ni)
    bN[ni] = *(const half8*)(Ibase + bOff + 2048 + ni * 1024);
  bOff += 4096;   // now points at k2

#pragma unroll
  for (int phase = 0; phase < 2; ++phase) {
    __syncthreads();  // phase 1: prior phase's a-frag reads complete
#pragma unroll
    for (int j = 0; j < 8; ++j) {
      const char* src = ((j & 1) ? gQ1 : gQ0) + (j >> 1) * 16384 + phase * 512;
      lds_load16(src, sA + ldst + j * 4096);
    }
    __syncthreads();  // staged image visible (compiler drains vmcnt)

    // preload a(k16=0): c = half
#pragma unroll
    for (int mi = 0; mi < 2; ++mi)
      aC[mi] = *(const half8*)(sA + mi * 16384 + aRowB + ((half ^ swz) << 4));

#pragma unroll
    for (int kl = 0; kl < 16; ++kl) {
      // depth-2 B prefetch (last ksteps over-read into PART: in-bounds, unused)
#pragma unroll
      for (int ni = 0; ni < 2; ++ni)
        bN2[ni] = *(const half8*)(Ibase + bOff + ni * 1024);
      bOff += 2048;
      if (kl + 1 < 16) {
        const int cN = ((((kl + 1) << 1) | half) ^ swz) << 4;
#pragma unroll
        for (int mi = 0; mi < 2; ++mi)
          aN[mi] = *(const half8*)(sA + mi * 16384 + aRowB + cN);
      }
#pragma unroll
      for (int mi = 0; mi < 2; ++mi)
#pragma unroll
        for (int ni = 0; ni < 2; ++ni)
          acc[mi][ni] = __builtin_amdgcn_mfma_f32_32x32x16_f16(
              aC[mi], bC[ni], acc[mi][ni], 0, 0, 0);
      if (kl + 1 < 16) {
#pragma unroll
        for (int x = 0; x < 2; ++x) aC[x] = aN[x];
      }
#pragma unroll
      for (int x = 0; x < 2; ++x) { bC[x] = bN[x]; bN[x] = bN2[x]; }
    }
  }

  // ---- epilogue: packed (score | 12-bit global idx) top-2 per query row ----
  // C/D: row = mi*32 + (r&3) + 8*(r>>2) + 4*half, col item = loc.
  // Each 32-lane group holds one row's 64 item-scores (2 ni x 32 lanes):
  // local top-2 over ni, then 5-step ds_swizzle butterfly over 32 lanes.
  const int e = isplit * 4 + wave;
  float2* part = (float2*)(ws + PART_OFF);
  const int locBase = isplit * 256 + wave * 64 + l31;   // + ni*32

#pragma unroll
  for (int mi = 0; mi < 2; ++mi) {
    float t1[16], t2[16];
#pragma unroll
    for (int r = 0; r < 16; ++r) {
      const float pv0 = __int_as_float(
          (__float_as_int(acc[mi][0][r]) & 0xFFFFF000) | locBase);
      const float pv1 = __int_as_float(
          (__float_as_int(acc[mi][1][r]) & 0xFFFFF000) | (locBase + 32));
      t1[r] = fmaxf(pv0, pv1);
      t2[r] = fminf(pv0, pv1);
    }

    // butterfly over 32-lane group (BitMode: (xor<<10)|0x1F), t1>=t2:
    //   t2' = med3(t1, o1, max(t2,o2)) = max(min(t1,o1), max(t2,o2))
#define BSTEP(SWZ)                                                       \
    {                                                                    \
      _Pragma("unroll") for (int r = 0; r < 16; ++r) {                   \
        const float o1 = swz_f<SWZ>(t1[r]);                              \
        const float o2 = swz_f<SWZ>(t2[r]);                              \
        t2[r] = __builtin_amdgcn_fmed3f(t1[r], o1, fmaxf(t2[r], o2));    \
        t1[r] = fmaxf(t1[r], o1);                                        \
      }                                                                  \
    }
    BSTEP(0x041F)   // xor 1
    BSTEP(0x081F)   // xor 2
    BSTEP(0x101F)   // xor 4
    BSTEP(0x201F)   // xor 8
    BSTEP(0x401F)   // xor 16
#undef BSTEP

    // writers: lanes 0 and 32 (one per half) write 16 rows each.
    if (l31 == 0) {
#pragma unroll
      for (int r = 0; r < 16; ++r) {
        const int qrow = qtile * BM + mi * 32 + (r & 3) + ((r >> 2) << 3) +
                         (half << 2);
        part[(size_t)qrow * 64 + e] = make_float2(t1[r], t2[r]);
      }
    }
  }
}

// ---------------- kernel 3: merge partials + exact fp32 rescue --------------
// one wave per query: 64 packed entries (1/lane) -> global fp16 top-2.
// If the packed gap exceeds 0.25 (>>5 sigma of fp16+quant score error),
// candidate 1 is certainly the true argmax: skip the 2nd gather entirely
// (wave-uniform branch). Otherwise exact fp32 re-score of both.
__global__ __launch_bounds__(256) void rescue_kernel(
    const float* __restrict__ q, const float* __restrict__ items,
    const char* __restrict__ ws, float* __restrict__ out) {
  const int wave = threadIdx.x >> 6;
  const int lane = threadIdx.x & 63;
  const int qrow = blockIdx.x * 4 + wave;

  const float2* part = (const float2*)(ws + PART_OFF);
  float2 ent = part[(size_t)qrow * 64 + lane];  // coalesced 512B burst
  float t1 = ent.x, t2 = ent.y;

#pragma unroll
  for (int m = 1; m < 64; m <<= 1) {
    const float o1 = __shfl_xor(t1, m, 64);
    const float o2 = __shfl_xor(t2, m, 64);
    const float mn = fminf(t1, o1);
    t1 = fmaxf(t1, o1);
    t2 = fmaxf(fmaxf(t2, o2), mn);
  }
  const int c1i = __float_as_int(t1) & 0xFFF;
  const int c2i = __float_as_int(t2) & 0xFFF;
  const bool need2 = (t1 - t2) < 0.25f;   // wave-uniform

  const float4* qp = (const float4*)(q + (size_t)qrow * CD);
  const float4* p1 = (const float4*)(items + (size_t)c1i * CD);
  float4 qa = qp[lane * 2], qb = qp[lane * 2 + 1];
  float4 xa = p1[lane * 2], xb = p1[lane * 2 + 1];

  float d1 = qa.x * xa.x + qa.y * xa.y + qa.z * xa.z + qa.w * xa.w +
             qb.x * xb.x + qb.y * xb.y + qb.z * xb.z + qb.w * xb.w;
  float qq = qa.x * qa.x + qa.y * qa.y + qa.z * qa.z + qa.w * qa.w +
             qb.x * qb.x + qb.y * qb.y + qb.z * qb.z + qb.w * qb.w;
  float i1 = xa.x * xa.x + xa.y * xa.y + xa.z * xa.z + xa.w * xa.w +
             xb.x * xb.x + xb.y * xb.y + xb.z * xb.z + xb.w * xb.w;

#pragma unroll
  for (int m = 1; m < 64; m <<= 1) {
    d1 += __shfl_xor(d1, m, 64);
    qq += __shfl_xor(qq, m, 64);
    i1 += __shfl_xor(i1, m, 64);
  }

  float d = d1, nn = i1;
  if (need2) {
    const float4* p2 = (const float4*)(items + (size_t)c2i * CD);
    float4 ya = p2[lane * 2], yb = p2[lane * 2 + 1];
    float d2 = qa.x * ya.x + qa.y * ya.y + qa.z * ya.z + qa.w * ya.w +
               qb.x * yb.x + qb.y * yb.y + qb.z * yb.z + qb.w * yb.w;
    float i2 = ya.x * ya.x + ya.y * ya.y + ya.z * ya.z + ya.w * ya.w +
               yb.x * yb.x + yb.y * yb.y + yb.z * yb.z + yb.w * yb.w;
#pragma unroll
    for (int m = 1; m < 64; m <<= 1) {
      d2 += __shfl_xor(d2, m, 64);
      i2 += __shfl_xor(i2, m, 64);
    }
    const bool use2 = (d2 > d1) || (d2 == d1 && c2i < c1i);
    d  = use2 ? d2 : d1;
    nn = use2 ? i2 : i1;
  }

  if (lane == 0) {
    float nq = fmaxf(sqrtf(qq), 1e-12f);
    float np = fmaxf(sqrtf(nn), 1e-12f);
    out[qrow] = -(d / (nq * np));
  }
}

// ---------------------------------------------------------------------------
extern "C" void kernel_launch(void* const* d_in, const int* in_sizes, int n_in,
                              void* d_out, int out_size, void* d_ws,
                              size_t ws_size, hipStream_t stream) {
  const float* q  = (const float*)d_in[0];
  const float* it = (const float*)d_in[1];
  char* ws = (char*)d_ws;
  float* out = (float*)d_out;

  const int total = TQ * CD / 4 + MI * CD / 8;
  convert_kernel<<<(total + 255) / 256, 256, 0, stream>>>(q, it, ws);
  dim3 grid(TQ / BM, NIS);
  score_kernel<<<grid, 256, 0, stream>>>(ws);
  rescue_kernel<<<TQ / 4, 256, 0, stream>>>(q, it, ws, out);
}

// Round 6
// 170.152 us; speedup vs baseline: 1.1297x; 1.1297x over previous
//
#include <hip/hip_runtime.h>

// ---------------------------------------------------------------------------
// NearestSim: out[t] = -cos(q_t, items[argmax_j q_t . items_j])
// T=16384, M=4096, C=512, fp32 in/out.
// R17 = R14 core (16x16x32 4x4 wave tile, med3/ds_swizzle epilogue, saddr B
//       stream, 3 blocks/CU) + T3/T4 pipelined staging:
//   - K split into 4 sub-phases of K=128 (16KB A-image), double-buffered in
//     the same 32KB LDS; staging for phase p+1 issued BEFORE K-loop of p
//     (one full phase of cover, ~1200 cyc, vs 0 before).
//   - barriers are raw `s_waitcnt vmcnt(4); s_barrier` — counted, never
//     drains the depth-2 B prefetch queue (the m97 barrier-drain fix).
//     vmcnt(4) is safe: each stage group is older than >=4 later B-loads.
//   - s_setprio(1/0) around each 16-MFMA cluster (T5).
// R16 lesson: 32x32x16 2x2 shrank the per-kstep MFMA window to 128 cyc ->
// latency-exposed (106us). R14's 310-cyc window + pipelined barriers is the
// right shape.
// ---------------------------------------------------------------------------

#define TQ 16384
#define MI 4096
#define CD 512
#define NIS 16          // item splits; block covers 256 items
#define BM 64           // block query rows

typedef _Float16 half8   __attribute__((ext_vector_type(8)));
typedef _Float16 half4_t __attribute__((ext_vector_type(4)));
typedef float    float4t __attribute__((ext_vector_type(4)));

// workspace layout (bytes)
#define QH_OFF   (0u)
#define QH_BYTES ((unsigned)TQ * CD * 2u)          // 16 MB fp16 queries (row-major)
#define IH_OFF   (QH_OFF + QH_BYTES)
#define IH_BYTES ((unsigned)MI * CD * 2u)          // 4 MB fp16 items (fragment order)
#define PART_OFF (IH_OFF + IH_BYTES)
#define PART_BYTES ((unsigned)TQ * 64u * 8u)       // 8 MB: 64 float2 / query
// total 28 MB

__device__ __forceinline__ void lds_load16(const void* g, void* l) {
  __builtin_amdgcn_global_load_lds(
      (const __attribute__((address_space(1))) void*)g,
      (__attribute__((address_space(3))) void*)l, 16, 0, 0);
}

template <int SWZ>
__device__ __forceinline__ float swz_f(float x) {
  return __int_as_float(__builtin_amdgcn_ds_swizzle(__float_as_int(x), SWZ));
}

// ---------------- kernel 1: fp32 -> fp16 conversion -------------------------
// Q: row-major half4 copy. Items: fragment order (chunk = (tile16*16+kk)*64
// + lane; lane = quad*16+l15 holds row tile16*16+l15, cols kk*32+quad*8..+8).
__global__ __launch_bounds__(256) void convert_kernel(
    const float* __restrict__ q, const float* __restrict__ it,
    char* __restrict__ ws) {
  const int idx = blockIdx.x * 256 + threadIdx.x;
  const int QV = TQ * CD / 4;   // Q: one half4 per thread
  const int IC = MI * CD / 8;   // items: one 16B chunk per thread
  if (idx < QV) {
    float4 v = ((const float4*)q)[idx];
    half4_t h = {(_Float16)v.x, (_Float16)v.y, (_Float16)v.z, (_Float16)v.w};
    ((half4_t*)(ws + QH_OFF))[idx] = h;
  }
  const int ic = idx - QV;
  if (ic >= 0 && ic < IC) {
    const int tile = ic >> 10;          // 1024 chunks per 16-row tile
    const int rem  = ic & 1023;
    const int kk   = rem >> 6;
    const int lane = rem & 63;
    const int row  = tile * 16 + (lane & 15);
    const int col  = kk * 32 + (lane >> 4) * 8;
    const float4* s = (const float4*)(it + (size_t)row * CD + col);
    float4 v0 = s[0], v1 = s[1];
    half8 h = {(_Float16)v0.x, (_Float16)v0.y, (_Float16)v0.z, (_Float16)v0.w,
               (_Float16)v1.x, (_Float16)v1.y, (_Float16)v1.z, (_Float16)v1.w};
    *(half8*)(ws + IH_OFF + (size_t)ic * 16) = h;
  }
}

// ---------------- kernel 2: pipelined fused GEMM + packed top-2 -------------
// grid (TQ/BM, NIS), block 256 = 4 waves; wave tile 64q x 64i (4x4 MFMAs of
// 16x16x32, 64 acc). A image: 4 sub-phases of K=128, 16KB each, double-
// buffered in 32KB LDS. B direct global with depth-2 register prefetch.
// LDS image (per phase buf): row r (0..63) at r*256; 16 chunks of 16B per
// row; phys chunk = logical c ^ (r&15)  -> b128 reads ~2-way (free).
// Staging (4 instr/phase): instr j, thread t -> dest = buf*16384+j*4096+t*16
//   row = j*16 + (t>>4), phys chunk pc = t&15,
//   logical c = pc ^ (row&15) = (t&15) ^ ((t>>4)&15).
__global__ __launch_bounds__(256, 3) void score_kernel(char* __restrict__ ws) {
  __shared__ __align__(16) char sA[2][16384];  // 32 KB total

  const int tid  = threadIdx.x;
  const int lane = tid & 63;
  const int wave = tid >> 6;
  const int quad = lane >> 4;
  const int l15  = lane & 15;
  const int qtile = blockIdx.x;
  const int isplit = blockIdx.y;

  // staging source base: + j*16384 + phase*256
  const char* Qbase = ws + QH_OFF + (size_t)qtile * BM * 1024;
  const char* gQ = Qbase + (tid >> 4) * 1024 +
                   (((tid & 15) ^ ((tid >> 4) & 15)) * 16);
  const int ldst = tid * 16;  // + buf*16384 + j*4096

  // B stream: uniform base + per-lane voffset; tile(ni) = isplit*16+wave*4+ni
  const char* Ibase = ws + IH_OFF;
  int bOff[4];
#pragma unroll
  for (int ni = 0; ni < 4; ++ni)
    bOff[ni] = ((isplit * 16 + wave * 4 + ni) << 14) + lane * 16;

  // A fragment: byte = buf*16384 + mi*4096 + l15*256 + ((kl*4+quad)^l15)*16
  const int aBase = l15 * 256;

  float4t acc[4][4];
#pragma unroll
  for (int mi = 0; mi < 4; ++mi)
#pragma unroll
    for (int ni = 0; ni < 4; ++ni) acc[mi][ni] = (float4t){0.f, 0.f, 0.f, 0.f};

  half8 aC[4], aN[4], bC[4], bN[4], bN2[4];
  // preload b(kk=0,1) — issued before staging, drained by prologue WB
#pragma unroll
  for (int ni = 0; ni < 4; ++ni) bC[ni] = *(const half8*)(Ibase + bOff[ni]);
#pragma unroll
  for (int ni = 0; ni < 4; ++ni)
    bN[ni] = *(const half8*)(Ibase + bOff[ni] + 1024);

#define STAGE(ph, buf)                                                    \
  {                                                                       \
    _Pragma("unroll") for (int j = 0; j < 4; ++j)                         \
      lds_load16(gQ + j * 16384 + (ph) * 256,                             \
                 (char*)sA + (buf) * 16384 + j * 4096 + ldst);            \
  }

  // counted barrier: all but 4 newest VMEM ops complete -> the stage group
  // (older than >=4 later loads) is done; newest B prefetch stays in flight.
#define WB4() asm volatile("s_waitcnt vmcnt(4)\n\ts_barrier" ::: "memory")

#define KPHASE(ph, buf)                                                   \
  {                                                                       \
    const char* sB = (const char*)sA + (buf) * 16384 + aBase;             \
    _Pragma("unroll") for (int mi = 0; mi < 4; ++mi)                      \
      aC[mi] = *(const half8*)(sB + mi * 4096 + ((quad ^ l15) << 4));     \
    _Pragma("unroll") for (int kl = 0; kl < 4; ++kl) {                    \
      const int kk = (ph) * 4 + kl;                                       \
      if (kk + 2 < 16) {                                                  \
        _Pragma("unroll") for (int ni = 0; ni < 4; ++ni)                  \
          bN2[ni] = *(const half8*)(Ibase + bOff[ni] + 2048);             \
      }                                                                   \
      if (kl + 1 < 4) {                                                   \
        const int cN = ((((kl + 1) << 2) + quad) ^ l15) << 4;             \
        _Pragma("unroll") for (int mi = 0; mi < 4; ++mi)                  \
          aN[mi] = *(const half8*)(sB + mi * 4096 + cN);                  \
      }                                                                   \
      __builtin_amdgcn_s_setprio(1);                                      \
      _Pragma("unroll") for (int mi = 0; mi < 4; ++mi)                    \
        _Pragma("unroll") for (int ni = 0; ni < 4; ++ni)                  \
          acc[mi][ni] = __builtin_amdgcn_mfma_f32_16x16x32_f16(           \
              aC[mi], bC[ni], acc[mi][ni], 0, 0, 0);                      \
      __builtin_amdgcn_s_setprio(0);                                      \
      if (kl + 1 < 4) {                                                   \
        _Pragma("unroll") for (int x = 0; x < 4; ++x) aC[x] = aN[x];      \
      }                                                                   \
      _Pragma("unroll") for (int x = 0; x < 4; ++x) bC[x] = bN[x];        \
      if (kk + 2 < 16) {                                                  \
        _Pragma("unroll") for (int x = 0; x < 4; ++x) bN[x] = bN2[x];     \
      }                                                                   \
      _Pragma("unroll") for (int ni = 0; ni < 4; ++ni) bOff[ni] += 1024;  \
    }                                                                     \
  }

  STAGE(0, 0);
  STAGE(1, 1);
  WB4();            // stage(0) done (4 newer stage(1) loads may fly)
  KPHASE(0, 0);
  WB4();            // stage(1) done (newest B group stays in flight)
  STAGE(2, 0);      // b0 free: all waves passed the barrier after reading it
  KPHASE(1, 1);
  WB4();            // stage(2) done
  STAGE(3, 1);
  KPHASE(2, 0);
  WB4();            // stage(3) done
  KPHASE(3, 1);

#undef KPHASE
#undef WB4
#undef STAGE

  // ---- epilogue: packed (score | 12-bit global idx) top-2 per query row ----
  // C row = quad*4+r, col = l15. item = isplit*256 + wave*64 + ni*16 + l15.
  // t1 >= t2 invariant -> t2' = med3(pv, t1, t2), t1' = max(t1, pv).
  float t1[16], t2[16];

  const int locBase = isplit * 256 + wave * 64 + l15;
#pragma unroll
  for (int ni = 0; ni < 4; ++ni) {
    const int loc = locBase + ni * 16;
#pragma unroll
    for (int mi = 0; mi < 4; ++mi) {
#pragma unroll
      for (int r = 0; r < 4; ++r) {
        const int s = mi * 4 + r;
        const float pv = __int_as_float(
            (__float_as_int(acc[mi][ni][r]) & 0xFFFFF000) | loc);
        if (ni == 0) {
          t1[s] = pv;
          t2[s] = -1e30f;
        } else {
          t2[s] = __builtin_amdgcn_fmed3f(pv, t1[s], t2[s]);
          t1[s] = fmaxf(t1[s], pv);
        }
      }
    }
  }

  // 4-step butterfly across the 16-lane l15 group via ds_swizzle xor
  // patterns (BitMode: offset = (xor<<10)|0x1F). Disjoint partner sets:
  //   t2' = med3(t1, o1, max(t2, o2)) = max(min(t1,o1), max(t2,o2)).
#define BSTEP(SWZ)                                                       \
  {                                                                      \
    _Pragma("unroll") for (int s = 0; s < 16; ++s) {                     \
      const float o1 = swz_f<SWZ>(t1[s]);                                \
      const float o2 = swz_f<SWZ>(t2[s]);                                \
      t2[s] = __builtin_amdgcn_fmed3f(t1[s], o1, fmaxf(t2[s], o2));      \
      t1[s] = fmaxf(t1[s], o1);                                          \
    }                                                                    \
  }
  BSTEP(0x041F)   // xor 1
  BSTEP(0x081F)   // xor 2
  BSTEP(0x101F)   // xor 4
  BSTEP(0x201F)   // xor 8
#undef BSTEP

  // writer: l15 == 0; entry = isplit*4 + wave. 64 entries per query.
  if (l15 == 0) {
    float2* part = (float2*)(ws + PART_OFF);
    const int e = isplit * 4 + wave;
#pragma unroll
    for (int s = 0; s < 16; ++s) {
      const int qrow = qtile * BM + (s >> 2) * 16 + quad * 4 + (s & 3);
      part[(size_t)qrow * 64 + e] = make_float2(t1[s], t2[s]);
    }
  }
}

// ---------------- kernel 3: merge partials + exact fp32 rescue --------------
// one wave per query: 64 packed entries (1/lane) -> global fp16 top-2.
// If the packed gap exceeds 0.25 (>>5 sigma of fp16+quant score error),
// candidate 1 is certainly the true argmax: skip the 2nd gather entirely
// (wave-uniform branch). Otherwise exact fp32 re-score of both.
__global__ __launch_bounds__(256) void rescue_kernel(
    const float* __restrict__ q, const float* __restrict__ items,
    const char* __restrict__ ws, float* __restrict__ out) {
  const int wave = threadIdx.x >> 6;
  const int lane = threadIdx.x & 63;
  const int qrow = blockIdx.x * 4 + wave;

  const float2* part = (const float2*)(ws + PART_OFF);
  float2 ent = part[(size_t)qrow * 64 + lane];  // coalesced 512B burst
  float t1 = ent.x, t2 = ent.y;

#pragma unroll
  for (int m = 1; m < 64; m <<= 1) {
    const float o1 = __shfl_xor(t1, m, 64);
    const float o2 = __shfl_xor(t2, m, 64);
    const float mn = fminf(t1, o1);
    t1 = fmaxf(t1, o1);
    t2 = fmaxf(fmaxf(t2, o2), mn);
  }
  const int c1i = __float_as_int(t1) & 0xFFF;
  const int c2i = __float_as_int(t2) & 0xFFF;
  const bool need2 = (t1 - t2) < 0.25f;   // wave-uniform

  const float4* qp = (const float4*)(q + (size_t)qrow * CD);
  const float4* p1 = (const float4*)(items + (size_t)c1i * CD);
  float4 qa = qp[lane * 2], qb = qp[lane * 2 + 1];
  float4 xa = p1[lane * 2], xb = p1[lane * 2 + 1];

  float d1 = qa.x * xa.x + qa.y * xa.y + qa.z * xa.z + qa.w * xa.w +
             qb.x * xb.x + qb.y * xb.y + qb.z * xb.z + qb.w * xb.w;
  float qq = qa.x * qa.x + qa.y * qa.y + qa.z * qa.z + qa.w * qa.w +
             qb.x * qb.x + qb.y * qb.y + qb.z * qb.z + qb.w * qb.w;
  float i1 = xa.x * xa.x + xa.y * xa.y + xa.z * xa.z + xa.w * xa.w +
             xb.x * xb.x + xb.y * xb.y + xb.z * xb.z + xb.w * xb.w;

#pragma unroll
  for (int m = 1; m < 64; m <<= 1) {
    d1 += __shfl_xor(d1, m, 64);
    qq += __shfl_xor(qq, m, 64);
    i1 += __shfl_xor(i1, m, 64);
  }

  float d = d1, nn = i1;
  if (need2) {
    const float4* p2 = (const float4*)(items + (size_t)c2i * CD);
    float4 ya = p2[lane * 2], yb = p2[lane * 2 + 1];
    float d2 = qa.x * ya.x + qa.y * ya.y + qa.z * ya.z + qa.w * ya.w +
               qb.x * yb.x + qb.y * yb.y + qb.z * yb.z + qb.w * yb.w;
    float i2 = ya.x * ya.x + ya.y * ya.y + ya.z * ya.z + ya.w * ya.w +
               yb.x * yb.x + yb.y * yb.y + yb.z * yb.z + yb.w * yb.w;
#pragma unroll
    for (int m = 1; m < 64; m <<= 1) {
      d2 += __shfl_xor(d2, m, 64);
      i2 += __shfl_xor(i2, m, 64);
    }
    const bool use2 = (d2 > d1) || (d2 == d1 && c2i < c1i);
    d  = use2 ? d2 : d1;
    nn = use2 ? i2 : i1;
  }

  if (lane == 0) {
    float nq = fmaxf(sqrtf(qq), 1e-12f);
    float np = fmaxf(sqrtf(nn), 1e-12f);
    out[qrow] = -(d / (nq * np));
  }
}

// ---------------------------------------------------------------------------
extern "C" void kernel_launch(void* const* d_in, const int* in_sizes, int n_in,
                              void* d_out, int out_size, void* d_ws,
                              size_t ws_size, hipStream_t stream) {
  const float* q  = (const float*)d_in[0];
  const float* it = (const float*)d_in[1];
  char* ws = (char*)d_ws;
  float* out = (float*)d_out;

  const int total = TQ * CD / 4 + MI * CD / 8;
  convert_kernel<<<(total + 255) / 256, 256, 0, stream>>>(q, it, ws);
  dim3 grid(TQ / BM, NIS);
  score_kernel<<<grid, 256, 0, stream>>>(ws);
  rescue_kernel<<<TQ / 4, 256, 0, stream>>>(q, it, ws, out);
}